// Round 1
// baseline (419.003 us; speedup 1.0000x reference)
//
#include <hip/hip_runtime.h>
#include <math.h>

#define NN 100000   // nodes
#define NE 640000   // edges
#define DF 128      // feature dim
#define NG 128      // graphs
#define NF 64       // final out dim
#define MAXDEG 64   // slot table width (P(deg>64) ~ 1e-8 at lambda=6.4)

// ---------------- kernel 1: bucket edges by dst (counting-sort, no scan) ---
__global__ __launch_bounds__(256) void k_bucket(const int* __restrict__ ei,
                                                int* __restrict__ cnt,
                                                int* __restrict__ slot) {
    int e = blockIdx.x * 256 + threadIdx.x;
    if (e >= NE) return;
    int src = ei[e];        // edge_index[0][e]
    int dst = ei[NE + e];   // edge_index[1][e]
    int pos = atomicAdd(&cnt[dst], 1);
    if (pos < MAXDEG) slot[dst * MAXDEG + pos] = src;
}

// ---------------- kernel 2: neighbor-sum, one wave per node, no atomics ----
__global__ __launch_bounds__(256) void k_aggregate(const float* __restrict__ x,
                                                   const int* __restrict__ slot,
                                                   const int* __restrict__ cnt,
                                                   float* __restrict__ agg) {
    int node = blockIdx.x * 4 + (threadIdx.x >> 6);
    int lane = threadIdx.x & 63;
    if (node >= NN) return;
    // each lane preloads one slot entry; broadcast via shfl in the loop
    int srcs = slot[node * MAXDEG + lane];
    int c = cnt[node];
    if (c > MAXDEG) c = MAXDEG;
    const float2* x2 = (const float2*)x;
    float2 v = make_float2(0.f, 0.f);
    for (int e = 0; e < c; ++e) {
        int s = __shfl(srcs, e);                 // uniform broadcast
        float2 xv = x2[(size_t)s * 64 + lane];   // coalesced 512B row read
        v.x += xv.x;
        v.y += xv.y;
    }
    ((float2*)agg)[(size_t)node * 64 + lane] = v;  // raw sum; deg division fused later
}

// ---------------- kernel 3: fused dual GEMM + bias + relu ------------------
// h[n,j] = relu( sum_k (agg[n,k]/max(deg,1))*Wl[j,k] + x[n,k]*Wr[j,k] + bl[j] )
// A = [agg*invd | x]  (K=256),  B = [Wl ; Wr],  tiles BM=64 BN=128 BK=32
__global__ __launch_bounds__(256) void k_gemm(const float* __restrict__ agg,
                                              const float* __restrict__ x,
                                              const int* __restrict__ cnt,
                                              const float* __restrict__ Wl,
                                              const float* __restrict__ bl,
                                              const float* __restrict__ Wr,
                                              float* __restrict__ h) {
    __shared__ float A_s[32 * 68];    // [kk][m], stride 68 (pad 4, keeps 16B align)
    __shared__ float B_s[32 * 132];   // [kk][j], stride 132
    __shared__ float invd[64];
    int tid = threadIdx.x;
    int n0 = blockIdx.x * 64;
    if (tid < 64) {
        int node = n0 + tid;
        float d = 1.f;
        if (node < NN) d = fmaxf((float)cnt[node], 1.f);
        invd[tid] = 1.f / d;
    }
    __syncthreads();

    int mg = tid & 15;   // m-group: nodes mg*4 .. mg*4+3
    int jg = tid >> 4;   // j-group: cols jg*8 .. jg*8+7
    float acc[4][8] = {{0.f}};

    for (int kc = 0; kc < 8; ++kc) {
        bool isA = (kc < 4);                    // first 128 k from agg/Wl, rest x/Wr
        const float* srcA = isA ? agg : x;
        const float* W    = isA ? Wl : Wr;
        int kbase = (kc & 3) * 32;
        // stage A tile (transposed): 512 float4, 2 per thread
        #pragma unroll
        for (int i = 0; i < 2; ++i) {
            int idx = tid + i * 256;
            int m = idx >> 3, kk4 = idx & 7;
            int node = n0 + m;
            float4 v = make_float4(0.f, 0.f, 0.f, 0.f);
            if (node < NN) v = *(const float4*)&srcA[(size_t)node * 128 + kbase + kk4 * 4];
            float s = isA ? invd[m] : 1.f;
            int b = (kk4 * 4) * 68 + m;
            A_s[b]       = v.x * s;
            A_s[b + 68]  = v.y * s;
            A_s[b + 136] = v.z * s;
            A_s[b + 204] = v.w * s;
        }
        // stage B tile (transposed): 1024 float4, 4 per thread
        #pragma unroll
        for (int i = 0; i < 4; ++i) {
            int idx = tid + i * 256;
            int j = idx >> 3, kk4 = idx & 7;
            float4 v = *(const float4*)&W[j * 128 + kbase + kk4 * 4];
            int b = (kk4 * 4) * 132 + j;
            B_s[b]       = v.x;
            B_s[b + 132] = v.y;
            B_s[b + 264] = v.z;
            B_s[b + 396] = v.w;
        }
        __syncthreads();
        #pragma unroll
        for (int kk = 0; kk < 32; ++kk) {
            float a4[4], b8[8];
            *(float4*)a4       = *(const float4*)&A_s[kk * 68 + mg * 4];
            *(float4*)b8       = *(const float4*)&B_s[kk * 132 + jg * 8];
            *(float4*)(b8 + 4) = *(const float4*)&B_s[kk * 132 + jg * 8 + 4];
            #pragma unroll
            for (int m = 0; m < 4; ++m)
                #pragma unroll
                for (int j = 0; j < 8; ++j)
                    acc[m][j] = fmaf(a4[m], b8[j], acc[m][j]);
        }
        __syncthreads();
    }
    // epilogue: bias + relu + store
    float bv[8];
    *(float4*)bv       = *(const float4*)&bl[jg * 8];
    *(float4*)(bv + 4) = *(const float4*)&bl[jg * 8 + 4];
    #pragma unroll
    for (int m = 0; m < 4; ++m) {
        int node = n0 + mg * 4 + m;
        if (node < NN) {
            float o[8];
            #pragma unroll
            for (int j = 0; j < 8; ++j) o[j] = fmaxf(acc[m][j] + bv[j], 0.f);
            *(float4*)&h[(size_t)node * 128 + jg * 8]     = *(float4*)o;
            *(float4*)&h[(size_t)node * 128 + jg * 8 + 4] = *(float4*)(o + 4);
        }
    }
}

// ---------------- kernel 4: per-graph max/mean pool (batch is sorted) ------
__global__ __launch_bounds__(256) void k_pool(const float* __restrict__ h,
                                              const int* __restrict__ batch,
                                              float* __restrict__ pmax,
                                              float* __restrict__ pmean) {
    int g = blockIdx.x;
    int t = threadIdx.x;
    int j = t & 127;
    int half = t >> 7;
    // lower_bound(batch, g) and lower_bound(batch, g+1)
    int lo = 0, hi = NN;
    while (lo < hi) { int mid = (lo + hi) >> 1; if (batch[mid] < g) lo = mid + 1; else hi = mid; }
    int start = lo;
    hi = NN;
    while (lo < hi) { int mid = (lo + hi) >> 1; if (batch[mid] < g + 1) lo = mid + 1; else hi = mid; }
    int end = lo;
    float mx = -INFINITY, sm = 0.f;
    for (int n = start + half; n < end; n += 2) {
        float v = h[(size_t)n * 128 + j];
        mx = fmaxf(mx, v);
        sm += v;
    }
    __shared__ float smax[256], ssum[256];
    smax[t] = mx; ssum[t] = sm;
    __syncthreads();
    if (t < 128) {
        mx = fmaxf(smax[t], smax[t + 128]);
        sm = ssum[t] + ssum[t + 128];
        int c = end - start;
        pmax[g * 128 + j]  = mx;                       // -inf if empty (= segment_max identity)
        pmean[g * 128 + j] = sm / fmaxf((float)c, 1.f);
    }
}

// ---------------- kernel 5: head GEMM [G,256]@[256,F] ----------------------
__global__ __launch_bounds__(64) void k_head(const float* __restrict__ pmax,
                                             const float* __restrict__ pmean,
                                             const float* __restrict__ Wlin,
                                             const float* __restrict__ blin,
                                             float* __restrict__ out) {
    int g = blockIdx.x, f = threadIdx.x;
    float s = blin[f];
    const float* w = &Wlin[f * 256];
    #pragma unroll 4
    for (int c = 0; c < 128; ++c) s = fmaf(pmax[g * 128 + c], w[c], s);
    #pragma unroll 4
    for (int c = 0; c < 128; ++c) s = fmaf(pmean[g * 128 + c], w[128 + c], s);
    out[g * 64 + f] = s;
}

extern "C" void kernel_launch(void* const* d_in, const int* in_sizes, int n_in,
                              void* d_out, int out_size, void* d_ws, size_t ws_size,
                              hipStream_t stream) {
    const float* x     = (const float*)d_in[0];
    const int*   ei    = (const int*)d_in[1];
    const int*   batch = (const int*)d_in[2];
    const float* Wl    = (const float*)d_in[3];
    const float* bl    = (const float*)d_in[4];
    const float* Wr    = (const float*)d_in[5];
    const float* Wlin  = (const float*)d_in[6];
    const float* blin  = (const float*)d_in[7];
    float* out = (float*)d_out;

    // workspace layout (bytes), all 16B-aligned; total 128,540,672 B
    char* ws = (char*)d_ws;
    int*   cnt   = (int*)(ws);                 //    400,000 (padded to 409,600)
    int*   slot  = (int*)(ws + 409600);        // 25,600,000
    float* agg   = (float*)(ws + 26009600);    // 51,200,000
    float* h     = (float*)(ws + 77209600);    // 51,200,000
    float* pmax  = (float*)(ws + 128409600);   //     65,536
    float* pmean = (float*)(ws + 128475136);   //     65,536

    hipMemsetAsync(cnt, 0, NN * sizeof(int), stream);
    k_bucket<<<NE / 256, 256, 0, stream>>>(ei, cnt, slot);
    k_aggregate<<<NN / 4, 256, 0, stream>>>(x, slot, cnt, agg);
    k_gemm<<<(NN + 63) / 64, 256, 0, stream>>>(agg, x, cnt, Wl, bl, Wr, h);
    k_pool<<<NG, 256, 0, stream>>>(h, batch, pmax, pmean);
    k_head<<<NG, NF, 0, stream>>>(pmax, pmean, Wlin, blin, out);
}

// Round 2
// 322.868 us; speedup vs baseline: 1.2978x; 1.2978x over previous
//
#include <hip/hip_runtime.h>
#include <math.h>

#define NN 100000   // nodes
#define NE 640000   // edges
#define DF 128      // feature dim
#define NG 128      // graphs
#define NF 64       // final out dim
#define MAXDEG 64   // slot table width (P(deg>64) ~ 1e-8 at lambda=6.4)
#define SPLIT 32    // pool slices per graph

// ---------------- kernel 1: bucket edges by dst (counting-sort, no scan) ---
__global__ __launch_bounds__(256) void k_bucket(const int* __restrict__ ei,
                                                int* __restrict__ cnt,
                                                int* __restrict__ slot) {
    int e = blockIdx.x * 256 + threadIdx.x;
    if (e >= NE) return;
    int src = ei[e];        // edge_index[0][e]
    int dst = ei[NE + e];   // edge_index[1][e]
    int pos = atomicAdd(&cnt[dst], 1);
    if (pos < MAXDEG) slot[dst * MAXDEG + pos] = src;
}

// ---------------- kernel 2: neighbor-sum, one wave per node, no atomics ----
__global__ __launch_bounds__(256) void k_aggregate(const float* __restrict__ x,
                                                   const int* __restrict__ slot,
                                                   const int* __restrict__ cnt,
                                                   float* __restrict__ agg) {
    int node = blockIdx.x * 4 + (threadIdx.x >> 6);
    int lane = threadIdx.x & 63;
    if (node >= NN) return;
    int srcs = slot[node * MAXDEG + lane];
    int c = cnt[node];
    if (c > MAXDEG) c = MAXDEG;
    const float2* x2 = (const float2*)x;
    float2 v = make_float2(0.f, 0.f);
    for (int e = 0; e < c; ++e) {
        int s = __shfl(srcs, e);                 // uniform broadcast
        float2 xv = x2[(size_t)s * 64 + lane];   // coalesced 512B row read
        v.x += xv.x;
        v.y += xv.y;
    }
    ((float2*)agg)[(size_t)node * 64 + lane] = v;  // raw sum; deg division fused later
}

// ---------------- kernel 3: fused dual GEMM + bias + relu ------------------
// h[n,j] = relu( sum_k (agg[n,k]/max(deg,1))*Wl[j,k] + x[n,k]*Wr[j,k] + bl[j] )
__global__ __launch_bounds__(256) void k_gemm(const float* __restrict__ agg,
                                              const float* __restrict__ x,
                                              const int* __restrict__ cnt,
                                              const float* __restrict__ Wl,
                                              const float* __restrict__ bl,
                                              const float* __restrict__ Wr,
                                              float* __restrict__ h) {
    __shared__ float A_s[32 * 68];    // [kk][m], stride 68
    __shared__ float B_s[32 * 132];   // [kk][j], stride 132
    __shared__ float invd[64];
    int tid = threadIdx.x;
    int n0 = blockIdx.x * 64;
    if (tid < 64) {
        int node = n0 + tid;
        float d = 1.f;
        if (node < NN) d = fmaxf((float)cnt[node], 1.f);
        invd[tid] = 1.f / d;
    }
    __syncthreads();

    int mg = tid & 15;   // m-group: nodes mg*4 .. mg*4+3
    int jg = tid >> 4;   // j-group: cols jg*8 .. jg*8+7
    float acc[4][8] = {{0.f}};

    for (int kc = 0; kc < 8; ++kc) {
        bool isA = (kc < 4);                    // first 128 k from agg/Wl, rest x/Wr
        const float* srcA = isA ? agg : x;
        const float* W    = isA ? Wl : Wr;
        int kbase = (kc & 3) * 32;
        #pragma unroll
        for (int i = 0; i < 2; ++i) {
            int idx = tid + i * 256;
            int m = idx >> 3, kk4 = idx & 7;
            int node = n0 + m;
            float4 v = make_float4(0.f, 0.f, 0.f, 0.f);
            if (node < NN) v = *(const float4*)&srcA[(size_t)node * 128 + kbase + kk4 * 4];
            float s = isA ? invd[m] : 1.f;
            int b = (kk4 * 4) * 68 + m;
            A_s[b]       = v.x * s;
            A_s[b + 68]  = v.y * s;
            A_s[b + 136] = v.z * s;
            A_s[b + 204] = v.w * s;
        }
        #pragma unroll
        for (int i = 0; i < 4; ++i) {
            int idx = tid + i * 256;
            int j = idx >> 3, kk4 = idx & 7;
            float4 v = *(const float4*)&W[j * 128 + kbase + kk4 * 4];
            int b = (kk4 * 4) * 132 + j;
            B_s[b]       = v.x;
            B_s[b + 132] = v.y;
            B_s[b + 264] = v.z;
            B_s[b + 396] = v.w;
        }
        __syncthreads();
        #pragma unroll
        for (int kk = 0; kk < 32; ++kk) {
            float a4[4], b8[8];
            *(float4*)a4       = *(const float4*)&A_s[kk * 68 + mg * 4];
            *(float4*)b8       = *(const float4*)&B_s[kk * 132 + jg * 8];
            *(float4*)(b8 + 4) = *(const float4*)&B_s[kk * 132 + jg * 8 + 4];
            #pragma unroll
            for (int m = 0; m < 4; ++m)
                #pragma unroll
                for (int j = 0; j < 8; ++j)
                    acc[m][j] = fmaf(a4[m], b8[j], acc[m][j]);
        }
        __syncthreads();
    }
    float bv[8];
    *(float4*)bv       = *(const float4*)&bl[jg * 8];
    *(float4*)(bv + 4) = *(const float4*)&bl[jg * 8 + 4];
    #pragma unroll
    for (int m = 0; m < 4; ++m) {
        int node = n0 + mg * 4 + m;
        if (node < NN) {
            float o[8];
            #pragma unroll
            for (int j = 0; j < 8; ++j) o[j] = fmaxf(acc[m][j] + bv[j], 0.f);
            *(float4*)&h[(size_t)node * 128 + jg * 8]     = *(float4*)o;
            *(float4*)&h[(size_t)node * 128 + jg * 8 + 4] = *(float4*)(o + 4);
        }
    }
}

// ---------------- kernel 4a: pool stage 1 — (graph, slice) partials --------
__global__ __launch_bounds__(256) void k_pool1(const float* __restrict__ h,
                                               const int* __restrict__ batch,
                                               float* __restrict__ pmaxp,
                                               float* __restrict__ psump) {
    int g = blockIdx.x >> 5;          // graph
    int s = blockIdx.x & (SPLIT - 1); // slice
    int t = threadIdx.x;
    int j = t & 127;
    int half = t >> 7;
    // [start,end) of graph g in sorted batch
    int lo = 0, hi = NN;
    while (lo < hi) { int mid = (lo + hi) >> 1; if (batch[mid] < g) lo = mid + 1; else hi = mid; }
    int start = lo;
    hi = NN;
    while (lo < hi) { int mid = (lo + hi) >> 1; if (batch[mid] < g + 1) lo = mid + 1; else hi = mid; }
    int end = lo;
    int chunk = (end - start + SPLIT - 1) / SPLIT;
    int a = start + s * chunk;
    int b = a + chunk; if (b > end) b = end;
    float mx = -INFINITY, sm = 0.f;
    for (int n = a + half; n < b; n += 2) {
        float v = h[(size_t)n * 128 + j];
        mx = fmaxf(mx, v);
        sm += v;
    }
    __shared__ float smax[256], ssum[256];
    smax[t] = mx; ssum[t] = sm;
    __syncthreads();
    if (t < 128) {
        int o = (g * SPLIT + s) * 128 + j;
        pmaxp[o] = fmaxf(smax[t], smax[t + 128]);
        psump[o] = ssum[t] + ssum[t + 128];
    }
}

// ---------------- kernel 4b: pool stage 2 + head GEMM, fused ---------------
__global__ __launch_bounds__(128) void k_pool2head(const float* __restrict__ pmaxp,
                                                   const float* __restrict__ psump,
                                                   const int* __restrict__ batch,
                                                   const float* __restrict__ Wlin,
                                                   const float* __restrict__ blin,
                                                   float* __restrict__ out) {
    int g = blockIdx.x;
    int t = threadIdx.x;  // 128
    // count of graph g (wave-uniform binary search)
    int lo = 0, hi = NN;
    while (lo < hi) { int mid = (lo + hi) >> 1; if (batch[mid] < g) lo = mid + 1; else hi = mid; }
    int start = lo;
    hi = NN;
    while (lo < hi) { int mid = (lo + hi) >> 1; if (batch[mid] < g + 1) lo = mid + 1; else hi = mid; }
    int cntg = lo - start;
    float mx = -INFINITY, sm = 0.f;
    #pragma unroll 8
    for (int s = 0; s < SPLIT; ++s) {
        int o = (g * SPLIT + s) * 128 + t;
        mx = fmaxf(mx, pmaxp[o]);
        sm += psump[o];
    }
    __shared__ float z[256];
    z[t] = mx;
    z[128 + t] = sm / fmaxf((float)cntg, 1.f);
    __syncthreads();
    if (t < 64) {
        float acc = blin[t];
        const float* w = &Wlin[t * 256];
        #pragma unroll 8
        for (int c = 0; c < 256; ++c) acc = fmaf(z[c], w[c], acc);
        out[g * 64 + t] = acc;
    }
}

extern "C" void kernel_launch(void* const* d_in, const int* in_sizes, int n_in,
                              void* d_out, int out_size, void* d_ws, size_t ws_size,
                              hipStream_t stream) {
    const float* x     = (const float*)d_in[0];
    const int*   ei    = (const int*)d_in[1];
    const int*   batch = (const int*)d_in[2];
    const float* Wl    = (const float*)d_in[3];
    const float* bl    = (const float*)d_in[4];
    const float* Wr    = (const float*)d_in[5];
    const float* Wlin  = (const float*)d_in[6];
    const float* blin  = (const float*)d_in[7];
    float* out = (float*)d_out;

    // workspace layout (bytes); total 128,409,600 B (same footprint as the
    // proven-to-fit round-0 layout). Pool partials ALIAS agg (dead after gemm).
    char* ws = (char*)d_ws;
    int*   cnt   = (int*)(ws);                 //    400,000 (padded to 409,600)
    int*   slot  = (int*)(ws + 409600);        // 25,600,000
    float* agg   = (float*)(ws + 26009600);    // 51,200,000
    float* h     = (float*)(ws + 77209600);    // 51,200,000
    float* pmaxp = (float*)(ws + 26009600);    // 2,097,152 (aliases agg)
    float* psump = (float*)(ws + 28106752);    // 2,097,152 (aliases agg)

    hipMemsetAsync(cnt, 0, NN * sizeof(int), stream);
    k_bucket<<<NE / 256, 256, 0, stream>>>(ei, cnt, slot);
    k_aggregate<<<NN / 4, 256, 0, stream>>>(x, slot, cnt, agg);
    k_gemm<<<(NN + 63) / 64, 256, 0, stream>>>(agg, x, cnt, Wl, bl, Wr, h);
    k_pool1<<<NG * SPLIT, 256, 0, stream>>>(h, batch, pmaxp, psump);
    k_pool2head<<<NG, 128, 0, stream>>>(pmaxp, psump, batch, Wlin, blin, out);
}

// Round 3
// 278.378 us; speedup vs baseline: 1.5052x; 1.1598x over previous
//
#include <hip/hip_runtime.h>
#include <math.h>

#define NN 100000   // nodes
#define NE 640000   // edges
#define DF 128      // feature dim
#define NG 128      // graphs
#define NF 64       // final out dim
#define MAXDEG 64   // slot table width (P(deg>64) ~ 1e-8 at lambda=6.4)
#define SPLIT 32    // pool slices per graph

typedef __attribute__((ext_vector_type(8))) short short8;   // 8 bf16 (4 VGPRs)
typedef __attribute__((ext_vector_type(4))) float floatx4;  // MFMA accumulator

// round-to-nearest-even f32 -> bf16 bits
__device__ __forceinline__ unsigned short bf16_rne(float v) {
    unsigned u = __float_as_uint(v);
    return (unsigned short)((u + 0x7FFF + ((u >> 16) & 1)) >> 16);
}

// ---------------- kernel 1: bucket edges by dst (counting-sort, no scan) ---
__global__ __launch_bounds__(256) void k_bucket(const int* __restrict__ ei,
                                                int* __restrict__ cnt,
                                                int* __restrict__ slot) {
    int e = blockIdx.x * 256 + threadIdx.x;
    if (e >= NE) return;
    int src = ei[e];        // edge_index[0][e]
    int dst = ei[NE + e];   // edge_index[1][e]
    int pos = atomicAdd(&cnt[dst], 1);
    if (pos < MAXDEG) slot[dst * MAXDEG + pos] = src;
}

// ---------------- kernel 2: neighbor-sum, one wave per node, no atomics ----
__global__ __launch_bounds__(256) void k_aggregate(const float* __restrict__ x,
                                                   const int* __restrict__ slot,
                                                   const int* __restrict__ cnt,
                                                   float* __restrict__ agg) {
    int node = blockIdx.x * 4 + (threadIdx.x >> 6);
    int lane = threadIdx.x & 63;
    if (node >= NN) return;
    int srcs = slot[node * MAXDEG + lane];
    int c = cnt[node];
    if (c > MAXDEG) c = MAXDEG;
    const float2* x2 = (const float2*)x;
    float2 v = make_float2(0.f, 0.f);
    for (int e = 0; e < c; ++e) {
        int s = __shfl(srcs, e);                 // uniform broadcast
        float2 xv = x2[(size_t)s * 64 + lane];   // coalesced 512B row read
        v.x += xv.x;
        v.y += xv.y;
    }
    ((float2*)agg)[(size_t)node * 64 + lane] = v;  // raw sum; deg division fused later
}

// ---------------- kernel 2b: W -> bf16 hi/lo in MFMA-fragment order --------
// B[k][j]: k<128 -> Wl[j][k], else Wr[j][k-128].  Fragment layout:
// off = ((c*8 + nb)*64 + l)*8 + e  with c=k>>5, nb=j>>4,
// l = (j&15) + (((k>>3)&3)<<4), e = k&7   (lane l: col=l&15, k=(l>>4)*8+e)
__global__ __launch_bounds__(256) void k_prepW(const float* __restrict__ Wl,
                                               const float* __restrict__ Wr,
                                               unsigned short* __restrict__ Bhi,
                                               unsigned short* __restrict__ Blo) {
    int idx = blockIdx.x * 256 + threadIdx.x;
    if (idx >= 256 * 128) return;
    int k = idx >> 7;
    int j = idx & 127;
    float v = (k < 128) ? Wl[j * 128 + k] : Wr[j * 128 + (k - 128)];
    int c = k >> 5, nb = j >> 4;
    int l = (j & 15) + (((k >> 3) & 3) << 4);
    int e = k & 7;
    int off = ((c * 8 + nb) * 64 + l) * 8 + e;
    unsigned short hb = bf16_rne(v);
    float hf = __uint_as_float((unsigned)hb << 16);
    Bhi[off] = hb;
    Blo[off] = bf16_rne(v - hf);
}

// ---------------- kernel 3: fused dual GEMM via bf16-split MFMA ------------
// h[n,j] = relu( [agg*invd | x] @ [Wl;Wr]^T + bl ),  A*B ~ AhBh + AhBl + AlBh
// block: 64 rows x 128 cols, 4 waves in 2x2, mfma_f32_16x16x32_bf16
__global__ __launch_bounds__(256) void k_gemm_mfma(const float* __restrict__ agg,
                                                   const float* __restrict__ x,
                                                   const int* __restrict__ cnt,
                                                   const unsigned short* __restrict__ Bhi,
                                                   const unsigned short* __restrict__ Blo,
                                                   const float* __restrict__ bl,
                                                   float* __restrict__ h) {
    __shared__ unsigned short Ahi_s[4 * 64 * 8];  // [mb][lane][e], frag-linear
    __shared__ unsigned short Alo_s[4 * 64 * 8];
    __shared__ float invd[64];
    int tid = threadIdx.x;
    int n0 = blockIdx.x * 64;
    if (tid < 64) {
        int node = n0 + tid;
        invd[tid] = (node < NN) ? 1.f / fmaxf((float)cnt[node], 1.f) : 0.f;
    }
    int wave = tid >> 6, lane = tid & 63;
    int wm = wave >> 1, wn = wave & 1;  // 2x2 wave grid, wave tile 32x64

    floatx4 acc[2][4];
    #pragma unroll
    for (int m = 0; m < 2; ++m)
        #pragma unroll
        for (int n = 0; n < 4; ++n)
            acc[m][n] = (floatx4){0.f, 0.f, 0.f, 0.f};
    __syncthreads();

    for (int c = 0; c < 8; ++c) {
        const float* src = (c < 4) ? agg : x;
        int kbase = (c & 3) * 32;
        bool scale = (c < 4);
        // stage A tile 64x32 fp32 -> hi/lo bf16 in fragment order
        #pragma unroll
        for (int i = 0; i < 2; ++i) {
            int idx = tid + i * 256;       // 0..511
            int row = idx >> 3, k4 = idx & 7;
            int node = n0 + row;
            float4 v = make_float4(0.f, 0.f, 0.f, 0.f);
            if (node < NN) v = *(const float4*)&src[(size_t)node * 128 + kbase + k4 * 4];
            float s = scale ? invd[row] : 1.f;
            v.x *= s; v.y *= s; v.z *= s; v.w *= s;
            int mb = row >> 4;
            int l  = (row & 15) + ((k4 >> 1) << 4);
            int base = ((mb << 6) + l) * 8 + ((k4 & 1) << 2);
            unsigned short h0 = bf16_rne(v.x), h1 = bf16_rne(v.y),
                           h2 = bf16_rne(v.z), h3 = bf16_rne(v.w);
            ushort4 hi4 = {h0, h1, h2, h3};
            ushort4 lo4 = {bf16_rne(v.x - __uint_as_float((unsigned)h0 << 16)),
                           bf16_rne(v.y - __uint_as_float((unsigned)h1 << 16)),
                           bf16_rne(v.z - __uint_as_float((unsigned)h2 << 16)),
                           bf16_rne(v.w - __uint_as_float((unsigned)h3 << 16))};
            *(ushort4*)&Ahi_s[base] = hi4;   // 8B aligned ds_write_b64
            *(ushort4*)&Alo_s[base] = lo4;
        }
        __syncthreads();
        // A frags for this wave (conflict-free b128: consecutive lanes -> consecutive 16B)
        short8 ah[2], al[2];
        #pragma unroll
        for (int m = 0; m < 2; ++m) {
            int mb = wm * 2 + m;
            ah[m] = *(const short8*)&Ahi_s[((mb << 6) + lane) * 8];
            al[m] = *(const short8*)&Alo_s[((mb << 6) + lane) * 8];
        }
        #pragma unroll
        for (int n = 0; n < 4; ++n) {
            int nb = wn * 4 + n;
            int off = ((c * 8 + nb) * 64 + lane) * 8;
            short8 bh = *(const short8*)&Bhi[off];   // L2-resident, coalesced 16B/lane
            short8 bo = *(const short8*)&Blo[off];
            #pragma unroll
            for (int m = 0; m < 2; ++m) {
                acc[m][n] = __builtin_amdgcn_mfma_f32_16x16x32_bf16(ah[m], bh, acc[m][n], 0, 0, 0);
                acc[m][n] = __builtin_amdgcn_mfma_f32_16x16x32_bf16(ah[m], bo, acc[m][n], 0, 0, 0);
                acc[m][n] = __builtin_amdgcn_mfma_f32_16x16x32_bf16(al[m], bh, acc[m][n], 0, 0, 0);
            }
        }
        __syncthreads();
    }
    // epilogue: bias + relu + store (C/D: col=lane&15, row=(lane>>4)*4+reg)
    #pragma unroll
    for (int n = 0; n < 4; ++n) {
        int nb = wn * 4 + n;
        int col = nb * 16 + (lane & 15);
        float bv = bl[col];
        #pragma unroll
        for (int m = 0; m < 2; ++m) {
            int mb = wm * 2 + m;
            #pragma unroll
            for (int r = 0; r < 4; ++r) {
                int row = mb * 16 + ((lane >> 4) << 2) + r;
                int node = n0 + row;
                if (node < NN)
                    h[(size_t)node * 128 + col] = fmaxf(acc[m][n][r] + bv, 0.f);
            }
        }
    }
}

// ---------------- kernel 4a: pool stage 1 — (graph, slice) partials --------
__global__ __launch_bounds__(256) void k_pool1(const float* __restrict__ h,
                                               const int* __restrict__ batch,
                                               float* __restrict__ pmaxp,
                                               float* __restrict__ psump) {
    int g = blockIdx.x >> 5;          // graph
    int s = blockIdx.x & (SPLIT - 1); // slice
    int t = threadIdx.x;
    int j = t & 127;
    int half = t >> 7;
    int lo = 0, hi = NN;
    while (lo < hi) { int mid = (lo + hi) >> 1; if (batch[mid] < g) lo = mid + 1; else hi = mid; }
    int start = lo;
    hi = NN;
    while (lo < hi) { int mid = (lo + hi) >> 1; if (batch[mid] < g + 1) lo = mid + 1; else hi = mid; }
    int end = lo;
    int chunk = (end - start + SPLIT - 1) / SPLIT;
    int a = start + s * chunk;
    int b = a + chunk; if (b > end) b = end;
    float mx = -INFINITY, sm = 0.f;
    for (int n = a + half; n < b; n += 2) {
        float v = h[(size_t)n * 128 + j];
        mx = fmaxf(mx, v);
        sm += v;
    }
    __shared__ float smax[256], ssum[256];
    smax[t] = mx; ssum[t] = sm;
    __syncthreads();
    if (t < 128) {
        int o = (g * SPLIT + s) * 128 + j;
        pmaxp[o] = fmaxf(smax[t], smax[t + 128]);
        psump[o] = ssum[t] + ssum[t + 128];
    }
}

// ---------------- kernel 4b: pool stage 2 + head GEMM, fused ---------------
__global__ __launch_bounds__(128) void k_pool2head(const float* __restrict__ pmaxp,
                                                   const float* __restrict__ psump,
                                                   const int* __restrict__ batch,
                                                   const float* __restrict__ Wlin,
                                                   const float* __restrict__ blin,
                                                   float* __restrict__ out) {
    int g = blockIdx.x;
    int t = threadIdx.x;  // 128
    int lo = 0, hi = NN;
    while (lo < hi) { int mid = (lo + hi) >> 1; if (batch[mid] < g) lo = mid + 1; else hi = mid; }
    int start = lo;
    hi = NN;
    while (lo < hi) { int mid = (lo + hi) >> 1; if (batch[mid] < g + 1) lo = mid + 1; else hi = mid; }
    int cntg = lo - start;
    float mx = -INFINITY, sm = 0.f;
    #pragma unroll 8
    for (int s = 0; s < SPLIT; ++s) {
        int o = (g * SPLIT + s) * 128 + t;
        mx = fmaxf(mx, pmaxp[o]);
        sm += psump[o];
    }
    __shared__ float z[256];
    z[t] = mx;
    z[128 + t] = sm / fmaxf((float)cntg, 1.f);
    __syncthreads();
    if (t < 64) {
        float acc = blin[t];
        const float* w = &Wlin[t * 256];
        #pragma unroll 8
        for (int c = 0; c < 256; ++c) acc = fmaf(z[c], w[c], acc);
        out[g * 64 + t] = acc;
    }
}

extern "C" void kernel_launch(void* const* d_in, const int* in_sizes, int n_in,
                              void* d_out, int out_size, void* d_ws, size_t ws_size,
                              hipStream_t stream) {
    const float* x     = (const float*)d_in[0];
    const int*   ei    = (const int*)d_in[1];
    const int*   batch = (const int*)d_in[2];
    const float* Wl    = (const float*)d_in[3];
    const float* bl    = (const float*)d_in[4];
    const float* Wr    = (const float*)d_in[5];
    const float* Wlin  = (const float*)d_in[6];
    const float* blin  = (const float*)d_in[7];
    float* out = (float*)d_out;

    // workspace layout (bytes); end = 128,539,136 <= proven round-0 footprint
    char* ws = (char*)d_ws;
    int*   cnt   = (int*)(ws);                        //    400,000 (pad 409,600)
    int*   slot  = (int*)(ws + 409600);               // 25,600,000
    float* agg   = (float*)(ws + 26009600);           // 51,200,000
    float* h     = (float*)(ws + 77209600);           // 51,200,000
    float* pmaxp = (float*)(ws + 26009600);           // 2,097,152 (aliases agg, dead after gemm)
    float* psump = (float*)(ws + 28106752);           // 2,097,152 (aliases agg)
    unsigned short* Bhi = (unsigned short*)(ws + 128409600);  // 65,536
    unsigned short* Blo = (unsigned short*)(ws + 128475136);  // 65,536

    hipMemsetAsync(cnt, 0, NN * sizeof(int), stream);
    k_prepW<<<128, 256, 0, stream>>>(Wl, Wr, Bhi, Blo);
    k_bucket<<<NE / 256, 256, 0, stream>>>(ei, cnt, slot);
    k_aggregate<<<NN / 4, 256, 0, stream>>>(x, slot, cnt, agg);
    k_gemm_mfma<<<(NN + 63) / 64, 256, 0, stream>>>(agg, x, cnt, Bhi, Blo, bl, h);
    k_pool1<<<NG * SPLIT, 256, 0, stream>>>(h, batch, pmaxp, psump);
    k_pool2head<<<NG, 128, 0, stream>>>(pmaxp, psump, batch, Wlin, blin, out);
}

// Round 4
// 239.922 us; speedup vs baseline: 1.7464x; 1.1603x over previous
//
#include <hip/hip_runtime.h>
#include <math.h>

#define NN 100000   // nodes
#define NE 640000   // edges
#define DF 128      // feature dim
#define NG 128      // graphs
#define NF 64       // final out dim
#define MAXDEG 32   // slot width; P(Poisson(6.4) > 32) ~ 1e-12 per node

typedef __attribute__((ext_vector_type(8))) short short8;   // 8 bf16 (4 VGPRs)
typedef __attribute__((ext_vector_type(4))) float floatx4;  // MFMA accumulator

// round-to-nearest-even f32 -> bf16 bits
__device__ __forceinline__ unsigned short bf16_rne(float v) {
    unsigned u = __float_as_uint(v);
    return (unsigned short)((u + 0x7FFF + ((u >> 16) & 1)) >> 16);
}

// ---------------- kernel 1: bucket edges by dst (counting-sort, no scan) ---
__global__ __launch_bounds__(256) void k_bucket(const int* __restrict__ ei,
                                                int* __restrict__ cnt,
                                                int* __restrict__ slot) {
    int e = blockIdx.x * 256 + threadIdx.x;
    if (e >= NE) return;
    int src = ei[e];        // edge_index[0][e]
    int dst = ei[NE + e];   // edge_index[1][e]
    int pos = atomicAdd(&cnt[dst], 1);
    if (pos < MAXDEG) slot[dst * MAXDEG + pos] = src;
}

// ---------------- kernel 2: neighbor-sum, 4 neighbors in flight per wave ---
// wave = one node; 4 groups of 16 lanes, group g loads neighbor e (e%4==g);
// lane i of a group holds cols i*8..i*8+7; cross-group shfl_xor reduce at end.
__global__ __launch_bounds__(256) void k_aggregate(const float* __restrict__ x,
                                                   const int* __restrict__ slot,
                                                   const int* __restrict__ cnt,
                                                   float* __restrict__ agg) {
    int node = blockIdx.x * 4 + (threadIdx.x >> 6);
    int lane = threadIdx.x & 63;
    if (node >= NN) return;
    int g = lane >> 4, i = lane & 15;
    int myidx = (lane < MAXDEG) ? slot[node * MAXDEG + lane] : 0;  // one 128B line
    int c = cnt[node];
    if (c > MAXDEG) c = MAXDEG;
    const float4* x4 = (const float4*)x;
    float4 a0 = make_float4(0.f, 0.f, 0.f, 0.f);
    float4 a1 = make_float4(0.f, 0.f, 0.f, 0.f);
    for (int e = g; e < c; e += 4) {
        int s = __shfl(myidx, e);
        size_t base = (size_t)s * 32 + i * 2;
        float4 v0 = x4[base];
        float4 v1 = x4[base + 1];
        a0.x += v0.x; a0.y += v0.y; a0.z += v0.z; a0.w += v0.w;
        a1.x += v1.x; a1.y += v1.y; a1.z += v1.z; a1.w += v1.w;
    }
    // reduce across the 4 groups (lanes i, i+16, i+32, i+48)
    #pragma unroll
    for (int k = 16; k <= 32; k <<= 1) {
        a0.x += __shfl_xor(a0.x, k); a0.y += __shfl_xor(a0.y, k);
        a0.z += __shfl_xor(a0.z, k); a0.w += __shfl_xor(a0.w, k);
        a1.x += __shfl_xor(a1.x, k); a1.y += __shfl_xor(a1.y, k);
        a1.z += __shfl_xor(a1.z, k); a1.w += __shfl_xor(a1.w, k);
    }
    if (g == 0) {
        float4* agg4 = (float4*)agg;
        size_t base = (size_t)node * 32 + i * 2;
        agg4[base] = a0;
        agg4[base + 1] = a1;
    }
}

// ---------------- kernel 2b: W -> bf16 hi/lo in MFMA-fragment order --------
__global__ __launch_bounds__(256) void k_prepW(const float* __restrict__ Wl,
                                               const float* __restrict__ Wr,
                                               unsigned short* __restrict__ Bhi,
                                               unsigned short* __restrict__ Blo) {
    int idx = blockIdx.x * 256 + threadIdx.x;
    if (idx >= 256 * 128) return;
    int k = idx >> 7;
    int j = idx & 127;
    float v = (k < 128) ? Wl[j * 128 + k] : Wr[j * 128 + (k - 128)];
    int c = k >> 5, nb = j >> 4;
    int l = (j & 15) + (((k >> 3) & 3) << 4);
    int e = k & 7;
    int off = ((c * 8 + nb) * 64 + l) * 8 + e;
    unsigned short hb = bf16_rne(v);
    float hf = __uint_as_float((unsigned)hb << 16);
    Bhi[off] = hb;
    Blo[off] = bf16_rne(v - hf);
}

// ---------------- kernel 3: dual GEMM (bf16-split MFMA) + fused pooling ----
// h = relu([agg*invd | x] @ [Wl;Wr]^T + bl)  -- never materialized; per-block
// per-graph (max,sum) partials merged into pmax/psum via atomics (h >= 0).
__global__ __launch_bounds__(256) void k_gemm_mfma(const float* __restrict__ agg,
                                                   const float* __restrict__ x,
                                                   const int* __restrict__ cnt,
                                                   const int* __restrict__ batch,
                                                   const unsigned short* __restrict__ Bhi,
                                                   const unsigned short* __restrict__ Blo,
                                                   const float* __restrict__ bl,
                                                   float* __restrict__ pmax,
                                                   float* __restrict__ psum) {
    __shared__ unsigned short Ahi_s[4 * 64 * 8];  // [mb][lane][e], frag-linear
    __shared__ unsigned short Alo_s[4 * 64 * 8];
    __shared__ float invd[64];
    __shared__ int sbatch[64];
    __shared__ float h_tile[64][132];             // padded: (row*132)%32 varies
    int tid = threadIdx.x;
    int n0 = blockIdx.x * 64;
    if (tid < 64) {
        int node = n0 + tid;
        invd[tid]   = (node < NN) ? 1.f / fmaxf((float)cnt[node], 1.f) : 0.f;
        sbatch[tid] = (node < NN) ? batch[node] : -1;
    }
    int wave = tid >> 6, lane = tid & 63;
    int wm = wave >> 1, wn = wave & 1;  // 2x2 wave grid, wave tile 32x64

    floatx4 acc[2][4];
    #pragma unroll
    for (int m = 0; m < 2; ++m)
        #pragma unroll
        for (int n = 0; n < 4; ++n)
            acc[m][n] = (floatx4){0.f, 0.f, 0.f, 0.f};
    __syncthreads();

    for (int c = 0; c < 8; ++c) {
        const float* src = (c < 4) ? agg : x;
        int kbase = (c & 3) * 32;
        bool scale = (c < 4);
        #pragma unroll
        for (int i = 0; i < 2; ++i) {
            int idx = tid + i * 256;       // 0..511
            int row = idx >> 3, k4 = idx & 7;
            int node = n0 + row;
            float4 v = make_float4(0.f, 0.f, 0.f, 0.f);
            if (node < NN) v = *(const float4*)&src[(size_t)node * 128 + kbase + k4 * 4];
            float s = scale ? invd[row] : 1.f;
            v.x *= s; v.y *= s; v.z *= s; v.w *= s;
            int mb = row >> 4;
            int l  = (row & 15) + ((k4 >> 1) << 4);
            int base = ((mb << 6) + l) * 8 + ((k4 & 1) << 2);
            unsigned short h0 = bf16_rne(v.x), h1 = bf16_rne(v.y),
                           h2 = bf16_rne(v.z), h3 = bf16_rne(v.w);
            ushort4 hi4 = {h0, h1, h2, h3};
            ushort4 lo4 = {bf16_rne(v.x - __uint_as_float((unsigned)h0 << 16)),
                           bf16_rne(v.y - __uint_as_float((unsigned)h1 << 16)),
                           bf16_rne(v.z - __uint_as_float((unsigned)h2 << 16)),
                           bf16_rne(v.w - __uint_as_float((unsigned)h3 << 16))};
            *(ushort4*)&Ahi_s[base] = hi4;
            *(ushort4*)&Alo_s[base] = lo4;
        }
        __syncthreads();
        short8 ah[2], al[2];
        #pragma unroll
        for (int m = 0; m < 2; ++m) {
            int mb = wm * 2 + m;
            ah[m] = *(const short8*)&Ahi_s[((mb << 6) + lane) * 8];
            al[m] = *(const short8*)&Alo_s[((mb << 6) + lane) * 8];
        }
        #pragma unroll
        for (int n = 0; n < 4; ++n) {
            int nb = wn * 4 + n;
            int off = ((c * 8 + nb) * 64 + lane) * 8;
            short8 bh = *(const short8*)&Bhi[off];
            short8 bo = *(const short8*)&Blo[off];
            #pragma unroll
            for (int m = 0; m < 2; ++m) {
                acc[m][n] = __builtin_amdgcn_mfma_f32_16x16x32_bf16(ah[m], bh, acc[m][n], 0, 0, 0);
                acc[m][n] = __builtin_amdgcn_mfma_f32_16x16x32_bf16(ah[m], bo, acc[m][n], 0, 0, 0);
                acc[m][n] = __builtin_amdgcn_mfma_f32_16x16x32_bf16(al[m], bh, acc[m][n], 0, 0, 0);
            }
        }
        __syncthreads();
    }
    // epilogue 1: bias + relu -> LDS tile (C/D: col=lane&15, row=(lane>>4)*4+r)
    #pragma unroll
    for (int n = 0; n < 4; ++n) {
        int nb = wn * 4 + n;
        int col = nb * 16 + (lane & 15);
        float bv = bl[col];
        #pragma unroll
        for (int m = 0; m < 2; ++m) {
            int mb = wm * 2 + m;
            #pragma unroll
            for (int r = 0; r < 4; ++r) {
                int row = mb * 16 + ((lane >> 4) << 2) + r;
                h_tile[row][col] = fmaxf(acc[m][n][r] + bv, 0.f);
            }
        }
    }
    __syncthreads();
    // epilogue 2: segmented per-graph (max,sum) over this block's rows
    {
        int col = tid & 127, half = tid >> 7;
        float mx = 0.f, sm = 0.f;
        int gcur = -2;
        for (int r = half * 32; r < half * 32 + 32; ++r) {
            int gb = sbatch[r];
            if (gb != gcur) {
                if (gcur >= 0) {
                    atomicMax((unsigned*)&pmax[gcur * 128 + col], __float_as_uint(mx));
                    atomicAdd(&psum[gcur * 128 + col], sm);
                }
                gcur = gb; mx = 0.f; sm = 0.f;
            }
            if (gb >= 0) {
                float v = h_tile[r][col];
                mx = fmaxf(mx, v);
                sm += v;
            }
        }
        if (gcur >= 0) {
            atomicMax((unsigned*)&pmax[gcur * 128 + col], __float_as_uint(mx));
            atomicAdd(&psum[gcur * 128 + col], sm);
        }
    }
}

// ---------------- kernel 4: pool finalize + head GEMM ----------------------
__global__ __launch_bounds__(128) void k_pool2head(const float* __restrict__ pmax,
                                                   const float* __restrict__ psum,
                                                   const int* __restrict__ batch,
                                                   const float* __restrict__ Wlin,
                                                   const float* __restrict__ blin,
                                                   float* __restrict__ out) {
    int g = blockIdx.x;
    int t = threadIdx.x;  // 128
    int lo = 0, hi = NN;
    while (lo < hi) { int mid = (lo + hi) >> 1; if (batch[mid] < g) lo = mid + 1; else hi = mid; }
    int start = lo;
    hi = NN;
    while (lo < hi) { int mid = (lo + hi) >> 1; if (batch[mid] < g + 1) lo = mid + 1; else hi = mid; }
    int cntg = lo - start;
    __shared__ float z[256];
    z[t]       = pmax[g * 128 + t];
    z[128 + t] = psum[g * 128 + t] / fmaxf((float)cntg, 1.f);
    __syncthreads();
    if (t < 64) {
        float acc = blin[t];
        const float* w = &Wlin[t * 256];
        #pragma unroll 8
        for (int c = 0; c < 256; ++c) acc = fmaf(z[c], w[c], acc);
        out[g * 64 + t] = acc;
    }
}

extern "C" void kernel_launch(void* const* d_in, const int* in_sizes, int n_in,
                              void* d_out, int out_size, void* d_ws, size_t ws_size,
                              hipStream_t stream) {
    const float* x     = (const float*)d_in[0];
    const int*   ei    = (const int*)d_in[1];
    const int*   batch = (const int*)d_in[2];
    const float* Wl    = (const float*)d_in[3];
    const float* bl    = (const float*)d_in[4];
    const float* Wr    = (const float*)d_in[5];
    const float* Wlin  = (const float*)d_in[6];
    const float* blin  = (const float*)d_in[7];
    float* out = (float*)d_out;

    // workspace layout (bytes); total ~64.8 MB (well under proven 128.4 MB)
    char* ws = (char*)d_ws;
    int*   cnt  = (int*)(ws);                         //    400,000 (pad 409,600)
    int*   slot = (int*)(ws + 409600);                // 12,800,000
    float* agg  = (float*)(ws + 13209600);            // 51,200,000
    float* pmax = (float*)(ws + 64409600);            //     65,536
    float* psum = (float*)(ws + 64475136);            //     65,536
    unsigned short* Bhi = (unsigned short*)(ws + 64540672);  // 65,536
    unsigned short* Blo = (unsigned short*)(ws + 64606208);  // 65,536

    hipMemsetAsync(cnt, 0, NN * sizeof(int), stream);
    hipMemsetAsync(pmax, 0, NG * 128 * sizeof(float), stream);  // valid: h >= 0
    hipMemsetAsync(psum, 0, NG * 128 * sizeof(float), stream);
    k_prepW<<<128, 256, 0, stream>>>(Wl, Wr, Bhi, Blo);
    k_bucket<<<NE / 256, 256, 0, stream>>>(ei, cnt, slot);
    k_aggregate<<<NN / 4, 256, 0, stream>>>(x, slot, cnt, agg);
    k_gemm_mfma<<<(NN + 63) / 64, 256, 0, stream>>>(agg, x, cnt, batch, Bhi, Blo, bl, pmax, psum);
    k_pool2head<<<NG, 128, 0, stream>>>(pmax, psum, batch, Wlin, blin, out);
}

// Round 5
// 229.883 us; speedup vs baseline: 1.8227x; 1.0437x over previous
//
#include <hip/hip_runtime.h>
#include <math.h>

#define NN 100000   // nodes (= 3125 * 32 exactly)
#define NE 640000   // edges
#define NG 128      // graphs
#define NF 64       // final out dim
#define MAXDEG 32   // slot width; P(Poisson(6.4) > 32) ~ 1e-12 per node

typedef __attribute__((ext_vector_type(8))) short short8;   // 8 bf16 (4 VGPRs)
typedef __attribute__((ext_vector_type(4))) float floatx4;  // MFMA accumulator

// round-to-nearest-even f32 -> bf16 bits
__device__ __forceinline__ unsigned short bf16_rne(float v) {
    unsigned u = __float_as_uint(v);
    return (unsigned short)((u + 0x7FFF + ((u >> 16) & 1)) >> 16);
}
// split pair (f0,f1) -> packed hi (2x bf16) and lo (2x bf16 of residual)
__device__ __forceinline__ void split2(float f0, float f1, unsigned& H, unsigned& L) {
    unsigned short h0 = bf16_rne(f0), h1 = bf16_rne(f1);
    float r0 = f0 - __uint_as_float((unsigned)h0 << 16);
    float r1 = f1 - __uint_as_float((unsigned)h1 << 16);
    H = (unsigned)h0 | ((unsigned)h1 << 16);
    L = (unsigned)bf16_rne(r0) | ((unsigned)bf16_rne(r1) << 16);
}

// ---------------- kernel 1: bucket edges by dst (counting-sort, no scan) ---
__global__ __launch_bounds__(256) void k_bucket(const int* __restrict__ ei,
                                                int* __restrict__ cnt,
                                                int* __restrict__ slot) {
    int e = blockIdx.x * 256 + threadIdx.x;
    if (e >= NE) return;
    int src = ei[e];        // edge_index[0][e]
    int dst = ei[NE + e];   // edge_index[1][e]
    int pos = atomicAdd(&cnt[dst], 1);
    if (pos < MAXDEG) slot[dst * MAXDEG + pos] = src;
}

// ---------------- kernel 2: W -> bf16 hi/lo in MFMA-fragment order ---------
__global__ __launch_bounds__(256) void k_prepW(const float* __restrict__ Wl,
                                               const float* __restrict__ Wr,
                                               unsigned short* __restrict__ Bhi,
                                               unsigned short* __restrict__ Blo) {
    int idx = blockIdx.x * 256 + threadIdx.x;
    if (idx >= 256 * 128) return;
    int k = idx >> 7;
    int j = idx & 127;
    float v = (k < 128) ? Wl[j * 128 + k] : Wr[j * 128 + (k - 128)];
    int c = k >> 5, nb = j >> 4;
    int l = (j & 15) + (((k >> 3) & 3) << 4);
    int e = k & 7;
    int off = ((c * 8 + nb) * 64 + l) * 8 + e;
    unsigned short hb = bf16_rne(v);
    float hf = __uint_as_float((unsigned)hb << 16);
    Bhi[off] = hb;
    Blo[off] = bf16_rne(v - hf);
}

// ---------------- kernel 3: FUSED gather + dual GEMM + pooling -------------
// Per block: 32 nodes. Gather neighbor sums in registers (16 lanes/node,
// lane i owns cols 8i..8i+7 == exactly one A-fragment slot), scale 1/deg,
// split to bf16 hi/lo, ds_write straight into fragment-ordered LDS.
// Then 2x2-wave MFMA (16x16x32, AhBh+AhBl+AlBh), bias+relu in-register,
// segmented per-graph (max,sum) reduced via shfl and merged with atomics.
__global__ __launch_bounds__(256) void k_fused(const float* __restrict__ x,
                                               const int* __restrict__ slot,
                                               const int* __restrict__ cnt,
                                               const int* __restrict__ batch,
                                               const unsigned short* __restrict__ Bhi,
                                               const unsigned short* __restrict__ Blo,
                                               const float* __restrict__ bl,
                                               float* __restrict__ pmax,
                                               float* __restrict__ psum) {
    __shared__ unsigned short Ahi_s[2 * 8 * 64 * 8];  // [mb][c][l][e] 16 KiB
    __shared__ unsigned short Alo_s[2 * 8 * 64 * 8];  // 16 KiB
    __shared__ int sbatch[32];
    int tid = threadIdx.x;
    int wave = tid >> 6, lane = tid & 63;
    int g = lane >> 4, i = lane & 15;
    int n0 = blockIdx.x * 32;
    if (tid < 32) sbatch[tid] = batch[n0 + tid];

    const float4* x4 = (const float4*)x;
    // -------- gather + stage: 2 passes x 4 nodes per wave ------------------
    for (int p = 0; p < 2; ++p) {
        int ln = wave * 8 + p * 4 + g;        // local node 0..31
        int n = n0 + ln;
        int ctrue = cnt[n];
        float inv = 1.f / fmaxf((float)ctrue, 1.f);
        int c = ctrue > MAXDEG ? MAXDEG : ctrue;
        int idx0 = slot[n * MAXDEG + i];
        int idx1 = slot[n * MAXDEG + 16 + i];
        int cmax = c;
        cmax = max(cmax, __shfl_xor(cmax, 16));
        cmax = max(cmax, __shfl_xor(cmax, 32));
        float4 a0 = make_float4(0.f, 0.f, 0.f, 0.f);
        float4 a1 = make_float4(0.f, 0.f, 0.f, 0.f);
        for (int e = 0; e < cmax; ++e) {
            int s = (e < 16) ? __shfl(idx0, (lane & 48) + e)
                             : __shfl(idx1, (lane & 48) + (e - 16));
            if (e < c) {
                float4 v0 = x4[(size_t)s * 32 + 2 * i];
                float4 v1 = x4[(size_t)s * 32 + 2 * i + 1];
                a0.x += v0.x; a0.y += v0.y; a0.z += v0.z; a0.w += v0.w;
                a1.x += v1.x; a1.y += v1.y; a1.z += v1.z; a1.w += v1.w;
            }
        }
        a0.x *= inv; a0.y *= inv; a0.z *= inv; a0.w *= inv;
        a1.x *= inv; a1.y *= inv; a1.z *= inv; a1.w *= inv;
        // fragment slot for this lane: mb=ln>>4, chunk=i>>2, l=(ln&15)+16*(i&3)
        int base = (((ln >> 4) * 8 + (i >> 2)) * 64 + (ln & 15) + ((i & 3) << 4)) * 8;
        uint4 H, L;
        split2(a0.x, a0.y, H.x, L.x);
        split2(a0.z, a0.w, H.y, L.y);
        split2(a1.x, a1.y, H.z, L.z);
        split2(a1.z, a1.w, H.w, L.w);
        *(uint4*)&Ahi_s[base] = H;
        *(uint4*)&Alo_s[base] = L;
        // self row x -> chunks 4..7 (k offset +128)
        float4 s0 = x4[(size_t)n * 32 + 2 * i];
        float4 s1 = x4[(size_t)n * 32 + 2 * i + 1];
        split2(s0.x, s0.y, H.x, L.x);
        split2(s0.z, s0.w, H.y, L.y);
        split2(s1.x, s1.y, H.z, L.z);
        split2(s1.z, s1.w, H.w, L.w);
        *(uint4*)&Ahi_s[base + 4 * 64 * 8] = H;
        *(uint4*)&Alo_s[base + 4 * 64 * 8] = L;
    }
    __syncthreads();

    // -------- MFMA phase: wave (wm,wn), tile 16 rows x 64 cols -------------
    int wm = wave >> 1, wn = wave & 1;
    floatx4 acc[4];
    #pragma unroll
    for (int n = 0; n < 4; ++n) acc[n] = (floatx4){0.f, 0.f, 0.f, 0.f};
    #pragma unroll
    for (int c = 0; c < 8; ++c) {
        short8 ah = *(const short8*)&Ahi_s[((wm * 8 + c) * 64 + lane) * 8];
        short8 al = *(const short8*)&Alo_s[((wm * 8 + c) * 64 + lane) * 8];
        #pragma unroll
        for (int n = 0; n < 4; ++n) {
            int nb = wn * 4 + n;
            int off = ((c * 8 + nb) * 64 + lane) * 8;
            short8 bh = *(const short8*)&Bhi[off];
            short8 bo = *(const short8*)&Blo[off];
            acc[n] = __builtin_amdgcn_mfma_f32_16x16x32_bf16(ah, bh, acc[n], 0, 0, 0);
            acc[n] = __builtin_amdgcn_mfma_f32_16x16x32_bf16(ah, bo, acc[n], 0, 0, 0);
            acc[n] = __builtin_amdgcn_mfma_f32_16x16x32_bf16(al, bh, acc[n], 0, 0, 0);
        }
    }

    // -------- epilogue: bias+relu, segmented pool, atomics -----------------
    // lane's rows: wm*16 + g*4 + r ; cols: wn*64 + n*16 + i
    int colb = wn * 64 + i;
    float v[4][4];
    #pragma unroll
    for (int n = 0; n < 4; ++n) {
        float bv = bl[colb + n * 16];
        #pragma unroll
        for (int r = 0; r < 4; ++r) v[n][r] = fmaxf(acc[n][r] + bv, 0.f);
    }
    int myg[4];
    #pragma unroll
    for (int r = 0; r < 4; ++r) myg[r] = sbatch[wm * 16 + g * 4 + r];
    int gfirst = sbatch[wm * 16];
    int glast  = sbatch[wm * 16 + 15];
    for (int gg = gfirst; gg <= glast; ++gg) {
        #pragma unroll
        for (int n = 0; n < 4; ++n) {
            float mx = 0.f, sm = 0.f;
            #pragma unroll
            for (int r = 0; r < 4; ++r) {
                if (myg[r] == gg) { mx = fmaxf(mx, v[n][r]); sm += v[n][r]; }
            }
            mx = fmaxf(mx, __shfl_xor(mx, 16));
            mx = fmaxf(mx, __shfl_xor(mx, 32));
            sm += __shfl_xor(sm, 16);
            sm += __shfl_xor(sm, 32);
            if (lane < 16) {
                atomicMax((unsigned*)&pmax[gg * 128 + colb + n * 16], __float_as_uint(mx));
                atomicAdd(&psum[gg * 128 + colb + n * 16], sm);
            }
        }
    }
}

// ---------------- kernel 4: pool finalize + head GEMM ----------------------
__global__ __launch_bounds__(128) void k_pool2head(const float* __restrict__ pmax,
                                                   const float* __restrict__ psum,
                                                   const int* __restrict__ batch,
                                                   const float* __restrict__ Wlin,
                                                   const float* __restrict__ blin,
                                                   float* __restrict__ out) {
    int g = blockIdx.x;
    int t = threadIdx.x;  // 128
    int lo = 0, hi = NN;
    while (lo < hi) { int mid = (lo + hi) >> 1; if (batch[mid] < g) lo = mid + 1; else hi = mid; }
    int start = lo;
    hi = NN;
    while (lo < hi) { int mid = (lo + hi) >> 1; if (batch[mid] < g + 1) lo = mid + 1; else hi = mid; }
    int cntg = lo - start;
    __shared__ float z[256];
    z[t]       = pmax[g * 128 + t];
    z[128 + t] = psum[g * 128 + t] / fmaxf((float)cntg, 1.f);
    __syncthreads();
    if (t < 64) {
        float acc = blin[t];
        const float* w = &Wlin[t * 256];
        #pragma unroll 8
        for (int c = 0; c < 256; ++c) acc = fmaf(z[c], w[c], acc);
        out[g * 64 + t] = acc;
    }
}

extern "C" void kernel_launch(void* const* d_in, const int* in_sizes, int n_in,
                              void* d_out, int out_size, void* d_ws, size_t ws_size,
                              hipStream_t stream) {
    const float* x     = (const float*)d_in[0];
    const int*   ei    = (const int*)d_in[1];
    const int*   batch = (const int*)d_in[2];
    const float* Wl    = (const float*)d_in[3];
    const float* bl    = (const float*)d_in[4];
    const float* Wr    = (const float*)d_in[5];
    const float* Wlin  = (const float*)d_in[6];
    const float* blin  = (const float*)d_in[7];
    float* out = (float*)d_out;

    // workspace layout (bytes); total ~13.5 MB
    char* ws = (char*)d_ws;
    int*   cnt  = (int*)(ws);                                //    400,000 (pad 409,600)
    int*   slot = (int*)(ws + 409600);                       // 12,800,000
    float* pmax = (float*)(ws + 13209600);                   //     65,536
    float* psum = (float*)(ws + 13275136);                   //     65,536
    unsigned short* Bhi = (unsigned short*)(ws + 13340672);  //     65,536
    unsigned short* Blo = (unsigned short*)(ws + 13406208);  //     65,536

    hipMemsetAsync(cnt, 0, NN * sizeof(int), stream);
    hipMemsetAsync(pmax, 0, NG * 128 * sizeof(float), stream);  // valid: h >= 0
    hipMemsetAsync(psum, 0, NG * 128 * sizeof(float), stream);
    k_prepW<<<128, 256, 0, stream>>>(Wl, Wr, Bhi, Blo);
    k_bucket<<<NE / 256, 256, 0, stream>>>(ei, cnt, slot);
    k_fused<<<NN / 32, 256, 0, stream>>>(x, slot, cnt, batch, Bhi, Blo, bl, pmax, psum);
    k_pool2head<<<NG, 128, 0, stream>>>(pmax, psum, batch, Wlin, blin, out);
}

// Round 6
// 211.562 us; speedup vs baseline: 1.9805x; 1.0866x over previous
//
#include <hip/hip_runtime.h>
#include <math.h>

#define NN 100000   // nodes (= 3125 * 32 exactly)
#define NE 640000   // edges
#define NG 128      // graphs
#define NF 64       // final out dim
#define MAXDEG 32   // slot width; P(Poisson(6.4) > 32) ~ 1e-12 per node

typedef __attribute__((ext_vector_type(8))) short short8;   // 8 bf16 (4 VGPRs)
typedef __attribute__((ext_vector_type(4))) float floatx4;  // MFMA accumulator

// round-to-nearest-even f32 -> bf16 bits
__device__ __forceinline__ unsigned short bf16_rne(float v) {
    unsigned u = __float_as_uint(v);
    return (unsigned short)((u + 0x7FFF + ((u >> 16) & 1)) >> 16);
}
// split pair (f0,f1) -> packed hi (2x bf16) and lo (2x bf16 of residual)
__device__ __forceinline__ void split2(float f0, float f1, unsigned& H, unsigned& L) {
    unsigned short h0 = bf16_rne(f0), h1 = bf16_rne(f1);
    float r0 = f0 - __uint_as_float((unsigned)h0 << 16);
    float r1 = f1 - __uint_as_float((unsigned)h1 << 16);
    H = (unsigned)h0 | ((unsigned)h1 << 16);
    L = (unsigned)bf16_rne(r0) | ((unsigned)bf16_rne(r1) << 16);
}

// ---------------- kernel 0: zero cnt + pmax + psum (replaces 3 memsets) ----
__global__ __launch_bounds__(256) void k_zero(int* __restrict__ cnt,
                                              float* __restrict__ pools) {
    int idx = blockIdx.x * 256 + threadIdx.x;
    if (idx < NN) cnt[idx] = 0;
    else if (idx < NN + 2 * NG * 128) pools[idx - NN] = 0.f;
}

// ---------------- kernel 1: bucket edges (blocks >=128) + prepW (blocks <128)
// prepW: B[k][j] (k<128 -> Wl[j][k], else Wr[j][k-128]) -> bf16 hi/lo in
// MFMA-fragment order: off = ((c*8+nb)*64 + l)*8 + e, c=k>>5, nb=j>>4,
// l=(j&15)+(((k>>3)&3)<<4), e=k&7.
__global__ __launch_bounds__(256) void k_prep(const int* __restrict__ ei,
                                              int* __restrict__ cnt,
                                              int* __restrict__ slot,
                                              const float* __restrict__ Wl,
                                              const float* __restrict__ Wr,
                                              unsigned short* __restrict__ Bhi,
                                              unsigned short* __restrict__ Blo) {
    if (blockIdx.x < 128) {
        int idx = blockIdx.x * 256 + threadIdx.x;   // 0..32767
        int k = idx >> 7;
        int j = idx & 127;
        float v = (k < 128) ? Wl[j * 128 + k] : Wr[j * 128 + (k - 128)];
        int c = k >> 5, nb = j >> 4;
        int l = (j & 15) + (((k >> 3) & 3) << 4);
        int e = k & 7;
        int off = ((c * 8 + nb) * 64 + l) * 8 + e;
        unsigned short hb = bf16_rne(v);
        float hf = __uint_as_float((unsigned)hb << 16);
        Bhi[off] = hb;
        Blo[off] = bf16_rne(v - hf);
    } else {
        int e = (blockIdx.x - 128) * 256 + threadIdx.x;
        if (e >= NE) return;
        int src = ei[e];        // edge_index[0][e]
        int dst = ei[NE + e];   // edge_index[1][e]
        int pos = atomicAdd(&cnt[dst], 1);
        if (pos < MAXDEG) slot[dst * MAXDEG + pos] = src;
    }
}

// ---------------- kernel 2: FUSED gather + dual GEMM + pooling -------------
// 32 nodes/block, 4 waves. Two phases over ONE 16.6KB LDS A-buffer:
//   A: neighbor-mean rows (k-chunks 0..3) staged + 48 MFMAs
//   B: self-x rows (k-chunks 4..7) staged into same LDS + 48 MFMAs
// Same accumulation order as the monolithic loop -> identical numerics.
// __launch_bounds__(256,8): 8 waves/EU -> 8 blocks/CU (LDS now allows it).
__global__ __launch_bounds__(256, 8) void k_fused(const float* __restrict__ x,
                                                  const int* __restrict__ slot,
                                                  const int* __restrict__ cnt,
                                                  const int* __restrict__ batch,
                                                  const unsigned short* __restrict__ Bhi,
                                                  const unsigned short* __restrict__ Blo,
                                                  const float* __restrict__ bl,
                                                  float* __restrict__ pmax,
                                                  float* __restrict__ psum) {
    __shared__ unsigned short Ahi_s[2 * 4 * 64 * 8];  // [mb][c(4)][l][e] 8 KiB
    __shared__ unsigned short Alo_s[2 * 4 * 64 * 8];  // 8 KiB
    __shared__ int sbatch[32];
    int tid = threadIdx.x;
    int wave = tid >> 6, lane = tid & 63;
    int g = lane >> 4, i = lane & 15;
    int n0 = blockIdx.x * 32;
    if (tid < 32) sbatch[tid] = batch[n0 + tid];

    const float4* x4 = (const float4*)x;
    int wm = wave >> 1, wn = wave & 1;
    floatx4 acc[4];
    #pragma unroll
    for (int n = 0; n < 4; ++n) acc[n] = (floatx4){0.f, 0.f, 0.f, 0.f};

    // -------- phase A: gather neighbor means -> chunks 0..3 ----------------
    for (int p = 0; p < 2; ++p) {
        int ln = wave * 8 + p * 4 + g;        // local node 0..31
        int n = n0 + ln;
        int ctrue = cnt[n];
        float inv = 1.f / fmaxf((float)ctrue, 1.f);
        int c = ctrue > MAXDEG ? MAXDEG : ctrue;
        int idx0 = slot[n * MAXDEG + i];
        int idx1 = slot[n * MAXDEG + 16 + i];
        int cmax = c;
        cmax = max(cmax, __shfl_xor(cmax, 16));
        cmax = max(cmax, __shfl_xor(cmax, 32));
        float4 a0 = make_float4(0.f, 0.f, 0.f, 0.f);
        float4 a1 = make_float4(0.f, 0.f, 0.f, 0.f);
        for (int e = 0; e < cmax; ++e) {
            int s = (e < 16) ? __shfl(idx0, (lane & 48) + e)
                             : __shfl(idx1, (lane & 48) + (e - 16));
            if (e < c) {
                float4 v0 = x4[(size_t)s * 32 + 2 * i];
                float4 v1 = x4[(size_t)s * 32 + 2 * i + 1];
                a0.x += v0.x; a0.y += v0.y; a0.z += v0.z; a0.w += v0.w;
                a1.x += v1.x; a1.y += v1.y; a1.z += v1.z; a1.w += v1.w;
            }
        }
        a0.x *= inv; a0.y *= inv; a0.z *= inv; a0.w *= inv;
        a1.x *= inv; a1.y *= inv; a1.z *= inv; a1.w *= inv;
        // fragment slot: mb=ln>>4, chunk=i>>2 (of 4), l=(ln&15)+16*(i&3)
        int base = (((ln >> 4) * 4 + (i >> 2)) * 64 + (ln & 15) + ((i & 3) << 4)) * 8;
        uint4 H, L;
        split2(a0.x, a0.y, H.x, L.x);
        split2(a0.z, a0.w, H.y, L.y);
        split2(a1.x, a1.y, H.z, L.z);
        split2(a1.z, a1.w, H.w, L.w);
        *(uint4*)&Ahi_s[base] = H;
        *(uint4*)&Alo_s[base] = L;
    }
    __syncthreads();
    #pragma unroll
    for (int c = 0; c < 4; ++c) {
        short8 ah = *(const short8*)&Ahi_s[((wm * 4 + c) * 64 + lane) * 8];
        short8 al = *(const short8*)&Alo_s[((wm * 4 + c) * 64 + lane) * 8];
        #pragma unroll
        for (int n = 0; n < 4; ++n) {
            int nb = wn * 4 + n;
            int off = ((c * 8 + nb) * 64 + lane) * 8;
            short8 bh = *(const short8*)&Bhi[off];
            short8 bo = *(const short8*)&Blo[off];
            acc[n] = __builtin_amdgcn_mfma_f32_16x16x32_bf16(ah, bh, acc[n], 0, 0, 0);
            acc[n] = __builtin_amdgcn_mfma_f32_16x16x32_bf16(ah, bo, acc[n], 0, 0, 0);
            acc[n] = __builtin_amdgcn_mfma_f32_16x16x32_bf16(al, bh, acc[n], 0, 0, 0);
        }
    }
    __syncthreads();   // all waves done reading before restage

    // -------- phase B: self rows -> same LDS, chunks 4..7 ------------------
    for (int p = 0; p < 2; ++p) {
        int ln = wave * 8 + p * 4 + g;
        int n = n0 + ln;
        float4 s0 = x4[(size_t)n * 32 + 2 * i];
        float4 s1 = x4[(size_t)n * 32 + 2 * i + 1];
        int base = (((ln >> 4) * 4 + (i >> 2)) * 64 + (ln & 15) + ((i & 3) << 4)) * 8;
        uint4 H, L;
        split2(s0.x, s0.y, H.x, L.x);
        split2(s0.z, s0.w, H.y, L.y);
        split2(s1.x, s1.y, H.z, L.z);
        split2(s1.z, s1.w, H.w, L.w);
        *(uint4*)&Ahi_s[base] = H;
        *(uint4*)&Alo_s[base] = L;
    }
    __syncthreads();
    #pragma unroll
    for (int c = 0; c < 4; ++c) {
        short8 ah = *(const short8*)&Ahi_s[((wm * 4 + c) * 64 + lane) * 8];
        short8 al = *(const short8*)&Alo_s[((wm * 4 + c) * 64 + lane) * 8];
        #pragma unroll
        for (int n = 0; n < 4; ++n) {
            int nb = wn * 4 + n;
            int off = (((c + 4) * 8 + nb) * 64 + lane) * 8;
            short8 bh = *(const short8*)&Bhi[off];
            short8 bo = *(const short8*)&Blo[off];
            acc[n] = __builtin_amdgcn_mfma_f32_16x16x32_bf16(ah, bh, acc[n], 0, 0, 0);
            acc[n] = __builtin_amdgcn_mfma_f32_16x16x32_bf16(ah, bo, acc[n], 0, 0, 0);
            acc[n] = __builtin_amdgcn_mfma_f32_16x16x32_bf16(al, bh, acc[n], 0, 0, 0);
        }
    }

    // -------- epilogue: bias+relu, segmented pool, atomics -----------------
    // lane's rows: wm*16 + g*4 + r ; cols: wn*64 + n*16 + i
    int colb = wn * 64 + i;
    float v[4][4];
    #pragma unroll
    for (int n = 0; n < 4; ++n) {
        float bv = bl[colb + n * 16];
        #pragma unroll
        for (int r = 0; r < 4; ++r) v[n][r] = fmaxf(acc[n][r] + bv, 0.f);
    }
    int myg[4];
    #pragma unroll
    for (int r = 0; r < 4; ++r) myg[r] = sbatch[wm * 16 + g * 4 + r];
    int gfirst = sbatch[wm * 16];
    int glast  = sbatch[wm * 16 + 15];
    for (int gg = gfirst; gg <= glast; ++gg) {
        #pragma unroll
        for (int n = 0; n < 4; ++n) {
            float mx = 0.f, sm = 0.f;
            #pragma unroll
            for (int r = 0; r < 4; ++r) {
                if (myg[r] == gg) { mx = fmaxf(mx, v[n][r]); sm += v[n][r]; }
            }
            mx = fmaxf(mx, __shfl_xor(mx, 16));
            mx = fmaxf(mx, __shfl_xor(mx, 32));
            sm += __shfl_xor(sm, 16);
            sm += __shfl_xor(sm, 32);
            if (lane < 16) {
                atomicMax((unsigned*)&pmax[gg * 128 + colb + n * 16], __float_as_uint(mx));
                atomicAdd(&psum[gg * 128 + colb + n * 16], sm);
            }
        }
    }
}

// ---------------- kernel 3: pool finalize + head GEMM ----------------------
__global__ __launch_bounds__(128) void k_pool2head(const float* __restrict__ pmax,
                                                   const float* __restrict__ psum,
                                                   const int* __restrict__ batch,
                                                   const float* __restrict__ Wlin,
                                                   const float* __restrict__ blin,
                                                   float* __restrict__ out) {
    int g = blockIdx.x;
    int t = threadIdx.x;  // 128
    int lo = 0, hi = NN;
    while (lo < hi) { int mid = (lo + hi) >> 1; if (batch[mid] < g) lo = mid + 1; else hi = mid; }
    int start = lo;
    hi = NN;
    while (lo < hi) { int mid = (lo + hi) >> 1; if (batch[mid] < g + 1) lo = mid + 1; else hi = mid; }
    int cntg = lo - start;
    __shared__ float z[256];
    z[t]       = pmax[g * 128 + t];
    z[128 + t] = psum[g * 128 + t] / fmaxf((float)cntg, 1.f);
    __syncthreads();
    if (t < 64) {
        float acc = blin[t];
        const float* w = &Wlin[t * 256];
        #pragma unroll 8
        for (int c = 0; c < 256; ++c) acc = fmaf(z[c], w[c], acc);
        out[g * 64 + t] = acc;
    }
}

extern "C" void kernel_launch(void* const* d_in, const int* in_sizes, int n_in,
                              void* d_out, int out_size, void* d_ws, size_t ws_size,
                              hipStream_t stream) {
    const float* x     = (const float*)d_in[0];
    const int*   ei    = (const int*)d_in[1];
    const int*   batch = (const int*)d_in[2];
    const float* Wl    = (const float*)d_in[3];
    const float* bl    = (const float*)d_in[4];
    const float* Wr    = (const float*)d_in[5];
    const float* Wlin  = (const float*)d_in[6];
    const float* blin  = (const float*)d_in[7];
    float* out = (float*)d_out;

    // workspace layout (bytes); total ~13.5 MB
    char* ws = (char*)d_ws;
    int*   cnt  = (int*)(ws);                                //    400,000 (pad 409,600)
    int*   slot = (int*)(ws + 409600);                       // 12,800,000
    float* pmax = (float*)(ws + 13209600);                   //     65,536
    float* psum = (float*)(ws + 13275136);                   //     65,536 (contiguous after pmax)
    unsigned short* Bhi = (unsigned short*)(ws + 13340672);  //     65,536
    unsigned short* Blo = (unsigned short*)(ws + 13406208);  //     65,536

    // 4 graph nodes total (was 7)
    k_zero<<<(NN + 2 * NG * 128 + 255) / 256, 256, 0, stream>>>(cnt, pmax);
    k_prep<<<128 + (NE + 255) / 256, 256, 0, stream>>>(ei, cnt, slot, Wl, Wr, Bhi, Blo);
    k_fused<<<NN / 32, 256, 0, stream>>>(x, slot, cnt, batch, Bhi, Blo, bl, pmax, psum);
    k_pool2head<<<NG, 128, 0, stream>>>(pmax, psum, batch, Wlin, blin, out);
}